// Round 9
// baseline (453.791 us; speedup 1.0000x reference)
//
#include <hip/hip_runtime.h>
#include <hip/hip_bf16.h>

#define HH   64
#define H2   128
#define VOC  64
#define LSEQ 2048

// ---------------------------------------------------------------------------
// Kernel 1: collapse embed -> FFN -> LN -> {kn, v, q} projections into
// per-token tables (VOCAB=64 entries of H=64 floats each).  (unchanged)
// ---------------------------------------------------------------------------
__global__ __launch_bounds__(128) void build_tables(
    const float* __restrict__ embed, const float* __restrict__ w1, const float* __restrict__ b1,
    const float* __restrict__ w2, const float* __restrict__ b2,
    const float* __restrict__ ln_g, const float* __restrict__ ln_b,
    const float* __restrict__ wk, const float* __restrict__ wv, const float* __restrict__ wq,
    float* __restrict__ kn_t, float* __restrict__ v_t, float* __restrict__ q_t)
{
    const int tok = blockIdx.x;
    const int tid = threadIdx.x;
    __shared__ float e_lds[HH];
    __shared__ float h_lds[H2];
    __shared__ float hs_lds[HH];

    if (tid < HH) e_lds[tid] = embed[tok * HH + tid];
    __syncthreads();

    {
        float s = b1[tid];
        #pragma unroll 8
        for (int i = 0; i < HH; ++i) s = fmaf(e_lds[i], w1[i * H2 + tid], s);
        h_lds[tid] = fmaxf(s, 0.f);
    }
    __syncthreads();

    if (tid < HH) {
        float f = b2[tid];
        #pragma unroll 8
        for (int j = 0; j < H2; ++j) f = fmaf(h_lds[j], w2[j * HH + tid], f);
        float x = e_lds[tid] + f;
        float sum = x, sq = x * x;
        #pragma unroll
        for (int m = 1; m < 64; m <<= 1) { sum += __shfl_xor(sum, m); sq += __shfl_xor(sq, m); }
        float mu  = sum * (1.f / HH);
        float var = sq * (1.f / HH) - mu * mu;
        hs_lds[tid] = (x - mu) * rsqrtf(var + 1e-5f) * ln_g[tid] + ln_b[tid];
    }
    __syncthreads();

    if (tid < HH) {
        float k = 0.f, v = 0.f, q = 0.f;
        #pragma unroll 8
        for (int j = 0; j < HH; ++j) {
            float h = hs_lds[j];
            k = fmaf(h, wk[j * HH + tid], k);
            v = fmaf(h, wv[j * HH + tid], v);
            q = fmaf(h, wq[j * HH + tid], q);
        }
        float kk = k * k;
        #pragma unroll
        for (int m = 1; m < 64; m <<= 1) kk += __shfl_xor(kk, m);
        float kn = k / fmaxf(sqrtf(kk), 1e-12f);
        kn_t[tok * HH + tid] = kn;
        v_t [tok * HH + tid] = v;
        q_t [tok * HH + tid] = q;
    }
}

// ---------------------------------------------------------------------------
// Kernel 1b: W[a][b] = kn_a . kn_b  (64x64 token-pair dot table, unchanged)
// ---------------------------------------------------------------------------
__global__ __launch_bounds__(64) void build_w(
    const float* __restrict__ kn_t, float* __restrict__ w_t)
{
    const int a = blockIdx.x, b = threadIdx.x;
    __shared__ float ka[HH];
    ka[b] = kn_t[a * HH + b];
    __syncthreads();
    const float4* kav = (const float4*)ka;
    const float4* kbv = (const float4*)(kn_t + b * HH);
    float4 s = {0.f, 0.f, 0.f, 0.f};
    #pragma unroll
    for (int j = 0; j < 16; ++j) {
        float4 x = kav[j], y = kbv[j];
        s.x = fmaf(x.x, y.x, s.x); s.y = fmaf(x.y, y.y, s.y);
        s.z = fmaf(x.z, y.z, s.z); s.w = fmaf(x.w, y.w, s.w);
    }
    w_t[a * VOC + b] = (s.x + s.y) + (s.z + s.w);
}

// ---------------------------------------------------------------------------
// Kernel 2 (NEW): backward vector scan.
//   r = M_final q = sum_t gamma_t v_t,  gamma_t = k_t . u_t,
//   u_t = prod_{s>t}(I - k_s k_s^T) q   (backward recurrence u -= (k.u) k).
// One wave per batch; u component i lives on lane i.  8-step groups:
//   c_j = k_(j).u_in   (8 independent dots, tree-reduced in parallel)
//   gamma_(j) = c_j - sum_{j'<j} gamma_(j') W[tok_j][tok_j']   (28 scalar FMA)
//   u -= sum gamma_(j) k_(j);  racc += sum gamma_(j) v_(j)
// Group g covers steps t = 2046-8g-j (j=0..7, descending t).
// Groups 0..254 full; group 255 = 7 real steps + 1 masked (j=7 unused).
// No LDS staging: k/v coalesced from L2-hot tables (lead-2 prefetch);
// tokens/G via uniform loads (scalar-eligible), leads 3/2.
// ---------------------------------------------------------------------------
__device__ __forceinline__ float rsum64(float x) {
    int q;
    q = __builtin_amdgcn_mov_dpp(__builtin_bit_cast(int, x), 0xB1, 0xF, 0xF, true);  // quad xor1
    x += __builtin_bit_cast(float, q);
    q = __builtin_amdgcn_mov_dpp(__builtin_bit_cast(int, x), 0x4E, 0xF, 0xF, true);  // quad xor2
    x += __builtin_bit_cast(float, q);
    q = __builtin_amdgcn_mov_dpp(__builtin_bit_cast(int, x), 0x141, 0xF, 0xF, true); // row_half_mirror (≡xor4)
    x += __builtin_bit_cast(float, q);
    q = __builtin_amdgcn_mov_dpp(__builtin_bit_cast(int, x), 0x140, 0xF, 0xF, true); // row_mirror (≡xor8)
    x += __builtin_bit_cast(float, q);
    x += __shfl_xor(x, 16);
    x += __shfl_xor(x, 32);
    return x;
}

#define GIDX(j, j2) ((j) * ((j) - 1) / 2 + (j2))

// load 8 tokens of group g into tk[slot][m], m = j (t = 2046-8g-j), clamped
#define LDTOK(slot, g)                                                       \
{                                                                            \
    const int base_ = 2046 - 8 * (g);                                        \
    _Pragma("unroll")                                                        \
    for (int m_ = 0; m_ < 8; ++m_) {                                         \
        int ix_ = base_ - m_;                                                \
        tk[slot][m_] = seq_b[ix_ < 0 ? 0 : ix_];                             \
    }                                                                        \
}

// gather the 28 strictly-lower Gram entries for a group (uniform loads)
#define LDG(gs, ts)                                                          \
{                                                                            \
    _Pragma("unroll")                                                        \
    for (int j_ = 1; j_ < 8; ++j_) {                                         \
        _Pragma("unroll")                                                    \
        for (int j2_ = 0; j2_ < j_; ++j2_)                                   \
            Gv[gs][GIDX(j_, j2_)] = w_t[tk[ts][j_] * VOC + tk[ts][j2_]];     \
    }                                                                        \
}

// prefetch k/v rows for a group (coalesced, lane = component)
#define LDKV(ks, ts)                                                         \
{                                                                            \
    _Pragma("unroll")                                                        \
    for (int j_ = 0; j_ < 8; ++j_) {                                         \
        kb[ks][j_] = kn_t[tk[ts][j_] * HH + lane];                           \
        vb[ks][j_] = v_t [tk[ts][j_] * HH + lane];                           \
    }                                                                        \
}

// process one group.  TAIL=1: skip j=7's updates (masked fake step).
#define PROC(ks, gs, TAIL)                                                   \
{                                                                            \
    float c_[8];                                                             \
    _Pragma("unroll")                                                        \
    for (int j_ = 0; j_ < 8; ++j_) c_[j_] = kb[ks][j_] * u;                  \
    _Pragma("unroll")                                                        \
    for (int j_ = 0; j_ < 8; ++j_) c_[j_] = rsum64(c_[j_]);                  \
    float gam_[8];                                                           \
    _Pragma("unroll")                                                        \
    for (int j_ = 0; j_ < 8; ++j_) {                                         \
        float cc_ = c_[j_];                                                  \
        _Pragma("unroll")                                                    \
        for (int j2_ = 0; j2_ < j_; ++j2_)                                   \
            cc_ = fmaf(-gam_[j2_], Gv[gs][GIDX(j_, j2_)], cc_);              \
        gam_[j_] = cc_;                                                      \
        if (!(TAIL) || j_ < 7) {                                             \
            u    = fmaf(-cc_, kb[ks][j_], u);                                \
            racc = fmaf( cc_, vb[ks][j_], racc);                             \
        }                                                                    \
    }                                                                        \
}

__global__ __launch_bounds__(64) void delta_scan_bw(
    const int* __restrict__ seq,
    const float* __restrict__ kn_t, const float* __restrict__ v_t, const float* __restrict__ q_t,
    const float* __restrict__ w_t,
    const float* __restrict__ wrp, const float* __restrict__ brp,
    const float* __restrict__ wout, const float* __restrict__ bout,
    float* __restrict__ out)
{
    __shared__ float r_lds[HH];
    __shared__ float t_lds[HH];

    const int b    = blockIdx.x;
    const int lane = threadIdx.x;            // component i
    const int* __restrict__ seq_b = seq + (long)b * LSEQ;

    // u = q_table[last token], racc = 0
    const int qtok = seq_b[LSEQ - 1];
    float u    = q_t[(long)qtok * HH + lane];
    float racc = 0.f;

    int   tk[3][8];
    float kb[3][8], vb[3][8];
    float Gv[3][28];

    // prologue: tokens for groups 0,1,2; G and k/v for groups 0,1
    LDTOK(0, 0) LDTOK(1, 1) LDTOK(2, 2)
    LDG(0, 0)  LDG(1, 1)
    LDKV(0, 0) LDKV(1, 1)

    // main loop: groups 0..254 (85 x 3, slots compile-time via unroll-by-3)
    for (int it = 0; it < 85; ++it) {
        const int g0 = 3 * it;
        {   // g = g0  (slot 0); prefetch tokens(g+3)->slot 0, G/kv(g+2)->slot 2
            if (g0 + 3 <= 255) LDTOK(0, g0 + 3)
            if (g0 + 2 <= 255) { LDG(2, 2) LDKV(2, 2) }
            PROC(0, 0, 0)
        }
        {   // g = g0+1 (slot 1); prefetch tokens(g+3)->slot 1, G/kv(g+2)->slot 0
            if (g0 + 4 <= 255) LDTOK(1, g0 + 4)
            if (g0 + 3 <= 255) { LDG(0, 0) LDKV(0, 0) }
            PROC(1, 1, 0)
        }
        {   // g = g0+2 (slot 2); prefetch tokens(g+3)->slot 2, G/kv(g+2)->slot 1
            if (g0 + 5 <= 255) LDTOK(2, g0 + 5)
            if (g0 + 4 <= 255) { LDG(1, 1) LDKV(1, 1) }
            PROC(2, 2, 0)
        }
    }
    // tail: group 255 (t = 6..0 real, j=7 masked); data sits in slot 255%3 = 0
    PROC(0, 0, 1)

    // ---- fused head: r -> wrp -> wout ----
    r_lds[lane] = racc;
    __syncthreads();

    {
        float s = brp[lane];
        #pragma unroll 8
        for (int ii = 0; ii < HH; ++ii) s = fmaf(r_lds[ii], wrp[ii * HH + lane], s);
        t_lds[lane] = s;
    }
    __syncthreads();

    {
        float s = bout[lane];
        #pragma unroll 8
        for (int h = 0; h < HH; ++h) s = fmaf(t_lds[h], wout[h * VOC + lane], s);
        out[(long)b * VOC + lane] = s;
    }
}

extern "C" void kernel_launch(void* const* d_in, const int* in_sizes, int n_in,
                              void* d_out, int out_size, void* d_ws, size_t ws_size,
                              hipStream_t stream)
{
    const int*   seq   = (const int*)  d_in[0];
    const float* embed = (const float*)d_in[1];
    const float* w1    = (const float*)d_in[2];
    const float* b1    = (const float*)d_in[3];
    const float* w2    = (const float*)d_in[4];
    const float* b2    = (const float*)d_in[5];
    const float* ln_g  = (const float*)d_in[6];
    const float* ln_b  = (const float*)d_in[7];
    const float* wk    = (const float*)d_in[8];
    const float* wv    = (const float*)d_in[9];
    const float* wq    = (const float*)d_in[10];
    const float* wrp   = (const float*)d_in[11];
    const float* brp   = (const float*)d_in[12];
    const float* wout  = (const float*)d_in[13];
    const float* bout  = (const float*)d_in[14];
    float* out = (float*)d_out;

    float* kn_t = (float*)d_ws;
    float* v_t  = kn_t + VOC * HH;
    float* q_t  = v_t  + VOC * HH;
    float* w_t  = q_t  + VOC * HH;

    const int B = in_sizes[0] / LSEQ;   // 256

    hipLaunchKernelGGL(build_tables, dim3(VOC), dim3(H2), 0, stream,
                       embed, w1, b1, w2, b2, ln_g, ln_b, wk, wv, wq,
                       kn_t, v_t, q_t);
    hipLaunchKernelGGL(build_w, dim3(VOC), dim3(HH), 0, stream, kn_t, w_t);
    hipLaunchKernelGGL(delta_scan_bw, dim3(B), dim3(HH), 0, stream,
                       seq, kn_t, v_t, q_t, w_t, wrp, brp, wout, bout, out);
}

// Round 10
// 245.846 us; speedup vs baseline: 1.8458x; 1.8458x over previous
//
#include <hip/hip_runtime.h>
#include <hip/hip_bf16.h>

#define HH   64
#define H2   128
#define VOC  64
#define LSEQ 2048

// ---------------------------------------------------------------------------
// Kernel 1: collapse embed -> FFN -> LN -> {kn, v, q} projections into
// per-token tables (VOCAB=64 entries of H=64 floats each).  (unchanged)
// ---------------------------------------------------------------------------
__global__ __launch_bounds__(128) void build_tables(
    const float* __restrict__ embed, const float* __restrict__ w1, const float* __restrict__ b1,
    const float* __restrict__ w2, const float* __restrict__ b2,
    const float* __restrict__ ln_g, const float* __restrict__ ln_b,
    const float* __restrict__ wk, const float* __restrict__ wv, const float* __restrict__ wq,
    float* __restrict__ kn_t, float* __restrict__ v_t, float* __restrict__ q_t)
{
    const int tok = blockIdx.x;
    const int tid = threadIdx.x;
    __shared__ float e_lds[HH];
    __shared__ float h_lds[H2];
    __shared__ float hs_lds[HH];

    if (tid < HH) e_lds[tid] = embed[tok * HH + tid];
    __syncthreads();

    {
        float s = b1[tid];
        #pragma unroll 8
        for (int i = 0; i < HH; ++i) s = fmaf(e_lds[i], w1[i * H2 + tid], s);
        h_lds[tid] = fmaxf(s, 0.f);
    }
    __syncthreads();

    if (tid < HH) {
        float f = b2[tid];
        #pragma unroll 8
        for (int j = 0; j < H2; ++j) f = fmaf(h_lds[j], w2[j * HH + tid], f);
        float x = e_lds[tid] + f;
        float sum = x, sq = x * x;
        #pragma unroll
        for (int m = 1; m < 64; m <<= 1) { sum += __shfl_xor(sum, m); sq += __shfl_xor(sq, m); }
        float mu  = sum * (1.f / HH);
        float var = sq * (1.f / HH) - mu * mu;
        hs_lds[tid] = (x - mu) * rsqrtf(var + 1e-5f) * ln_g[tid] + ln_b[tid];
    }
    __syncthreads();

    if (tid < HH) {
        float k = 0.f, v = 0.f, q = 0.f;
        #pragma unroll 8
        for (int j = 0; j < HH; ++j) {
            float h = hs_lds[j];
            k = fmaf(h, wk[j * HH + tid], k);
            v = fmaf(h, wv[j * HH + tid], v);
            q = fmaf(h, wq[j * HH + tid], q);
        }
        float kk = k * k;
        #pragma unroll
        for (int m = 1; m < 64; m <<= 1) kk += __shfl_xor(kk, m);
        float kn = k / fmaxf(sqrtf(kk), 1e-12f);
        kn_t[tok * HH + tid] = kn;
        v_t [tok * HH + tid] = v;
        q_t [tok * HH + tid] = q;
    }
}

// ---------------------------------------------------------------------------
// Kernel 1b: blocks 0..63:   W[a][b]  = kn_a . kn_b
//            blocks 64..127: CQ[a][b] = q_a  . kn_b
// ---------------------------------------------------------------------------
__global__ __launch_bounds__(64) void build_dots(
    const float* __restrict__ kn_t, const float* __restrict__ q_t,
    float* __restrict__ w_t, float* __restrict__ cq_t)
{
    const int aa = blockIdx.x, b = threadIdx.x;
    const bool isW = (aa < VOC);
    const int a = isW ? aa : aa - VOC;
    const float* xrow = isW ? (kn_t + a * HH) : (q_t + a * HH);
    __shared__ float xa[HH];
    xa[b] = xrow[b];
    __syncthreads();
    const float4* kav = (const float4*)xa;
    const float4* kbv = (const float4*)(kn_t + b * HH);
    float4 s = {0.f, 0.f, 0.f, 0.f};
    #pragma unroll
    for (int j = 0; j < 16; ++j) {
        float4 x = kav[j], y = kbv[j];
        s.x = fmaf(x.x, y.x, s.x); s.y = fmaf(x.y, y.y, s.y);
        s.z = fmaf(x.z, y.z, s.z); s.w = fmaf(x.w, y.w, s.w);
    }
    float r = (s.x + s.y) + (s.z + s.w);
    (isW ? w_t : cq_t)[a * VOC + b] = r;
}

// ---------------------------------------------------------------------------
// Kernel 1c: head tables.  VPW[b][o] = (v_b @ wrp) @ wout ; bo = brp@wout+bout
// ---------------------------------------------------------------------------
__global__ __launch_bounds__(64) void build_head(
    const float* __restrict__ v_t, const float* __restrict__ wrp, const float* __restrict__ brp,
    const float* __restrict__ wout, const float* __restrict__ bout,
    float* __restrict__ vpw_t, float* __restrict__ bo_t)
{
    const int b = blockIdx.x, o = threadIdx.x;
    __shared__ float vrow[HH], vp[HH];
    vrow[o] = v_t[b * HH + o];
    __syncthreads();
    float s = 0.f;
    #pragma unroll 8
    for (int i = 0; i < HH; ++i) s = fmaf(vrow[i], wrp[i * HH + o], s);
    vp[o] = s;
    __syncthreads();
    float s2 = 0.f;
    #pragma unroll 8
    for (int i = 0; i < HH; ++i) s2 = fmaf(vp[i], wout[i * VOC + o], s2);
    vpw_t[b * VOC + o] = s2;
    if (b == 0) {
        float t = bout[o];
        #pragma unroll 8
        for (int i = 0; i < HH; ++i) t = fmaf(brp[i], wout[i * VOC + o], t);
        bo_t[o] = t;
    }
}

// ---------------------------------------------------------------------------
// Kernel 2: token-bucketed backward gamma scan.  One wave per batch.
//   gamma_t = CQ[qtok][a_t] - W_row[a_t].S - sum_{j'<j in group} W[a_j][a_j'] gamma_j'
//   S[a_t] += gamma_t ;   out_o = sum_b S_b VPW[b][o] + bo[o]
// State = S (1 VGPR).  Groups of 8 backward steps; tokens prefetched 2 groups
// ahead (ring of 3), W-rows/cq 1 group ahead (ring of 2), Gram via readlane
// from the already-loaded W-rows (no extra loads).
// ---------------------------------------------------------------------------
__device__ __forceinline__ float bf64(float x) {
    int q;
    q = __builtin_amdgcn_mov_dpp(__builtin_bit_cast(int, x), 0xB1,  0xF, 0xF, true); x += __builtin_bit_cast(float, q); // xor1
    q = __builtin_amdgcn_mov_dpp(__builtin_bit_cast(int, x), 0x4E,  0xF, 0xF, true); x += __builtin_bit_cast(float, q); // xor2
    q = __builtin_amdgcn_mov_dpp(__builtin_bit_cast(int, x), 0x141, 0xF, 0xF, true); x += __builtin_bit_cast(float, q); // half_mirror
    q = __builtin_amdgcn_mov_dpp(__builtin_bit_cast(int, x), 0x140, 0xF, 0xF, true); x += __builtin_bit_cast(float, q); // mirror
    q = __builtin_amdgcn_ds_swizzle(__builtin_bit_cast(int, x), 0x401F);             x += __builtin_bit_cast(float, q); // xor16
    x += __shfl_xor(x, 32);                                                                                             // xor32
    return x;
}

// PROC: one 8-step group G.  ST=G%3 (this group's tokens), SP=(G+2)%3 (token
// prefetch dest), SNT=(G+1)%3 (tokens feeding W-row prefetch), SC=G%2 (this
// group's rows), SN=(G+1)%2.  PT/PW gate the prefetches, TAIL masks j=7.
#define PROC(G, ST, SP, SNT, SC, SN, PT, PW, TAIL)                           \
{                                                                            \
    if (PT) {                                                                \
        const int nb_ = 2046 - 8 * ((G) + 2);                                \
        _Pragma("unroll")                                                    \
        for (int j = 0; j < 8; ++j) {                                        \
            int tt = nb_ - j;                                                \
            a[SP][j] = seq_lds[tt < 0 ? 0 : tt];                             \
        }                                                                    \
    }                                                                        \
    if (PW) {                                                                \
        _Pragma("unroll")                                                    \
        for (int j = 0; j < 8; ++j) {                                        \
            wr[SN][j]  = w_lds[(a[SNT][j] << 6) + lane];                     \
            cqv[SN][j] = cq_lds[a[SNT][j]];                                  \
        }                                                                    \
    }                                                                        \
    float d_[8];                                                             \
    _Pragma("unroll")                                                        \
    for (int j = 0; j < 8; ++j) d_[j] = wr[SC][j] * S;                       \
    _Pragma("unroll")                                                        \
    for (int j = 0; j < 8; ++j) d_[j] = bf64(d_[j]);                         \
    int sa_[8];                                                              \
    _Pragma("unroll")                                                        \
    for (int j = 0; j < 8; ++j)                                              \
        sa_[j] = __builtin_amdgcn_readfirstlane(a[ST][j]);                   \
    float gm_[8];                                                            \
    _Pragma("unroll")                                                        \
    for (int j = 0; j < 8; ++j) {                                            \
        float g0_ = cqv[SC][j] - d_[j];                                      \
        _Pragma("unroll")                                                    \
        for (int j2 = 0; j2 < j; ++j2) {                                     \
            float G_ = __builtin_bit_cast(float,                             \
                __builtin_amdgcn_readlane(                                   \
                    __builtin_bit_cast(int, wr[SC][j]), sa_[j2]));           \
            g0_ = fmaf(-G_, gm_[j2], g0_);                                   \
        }                                                                    \
        gm_[j] = g0_;                                                        \
        if (!(TAIL) || j < 7)                                                \
            S += (lane == a[ST][j]) ? g0_ : 0.f;                             \
    }                                                                        \
}

__global__ __launch_bounds__(64) void delta_s_scan(
    const int* __restrict__ seq,
    const float* __restrict__ w_t, const float* __restrict__ cq_t,
    const float* __restrict__ vpw_t, const float* __restrict__ bo_t,
    float* __restrict__ out)
{
    __shared__ __align__(16) float w_lds[VOC * VOC];   // 16 KB
    __shared__ __align__(16) int   seq_lds[LSEQ];      // 8 KB
    __shared__ float cq_lds[VOC];
    __shared__ float s_lds[VOC];

    const int b    = blockIdx.x;
    const int lane = threadIdx.x;
    const int* __restrict__ seq_b = seq + (long)b * LSEQ;

    // stage W table + this batch's token row
    {
        const float4* s1 = (const float4*)w_t; float4* d1 = (float4*)w_lds;
        #pragma unroll
        for (int r = 0; r < 16; ++r) d1[lane + 64 * r] = s1[lane + 64 * r];
        const int4* s3 = (const int4*)seq_b; int4* d3 = (int4*)seq_lds;
        #pragma unroll
        for (int r = 0; r < 8; ++r) d3[lane + 64 * r] = s3[lane + 64 * r];
    }
    __syncthreads();
    {
        const int qtok = seq_lds[LSEQ - 1];
        cq_lds[lane] = cq_t[qtok * VOC + lane];
    }
    __syncthreads();

    float S = 0.f;
    int   a[3][8];
    float wr[2][8], cqv[2][8];

    // prologue: tokens for groups 0,1; W-rows/cq for group 0
    #pragma unroll
    for (int j = 0; j < 8; ++j) a[0][j] = seq_lds[2046 - j];
    #pragma unroll
    for (int j = 0; j < 8; ++j) a[1][j] = seq_lds[2038 - j];
    #pragma unroll
    for (int j = 0; j < 8; ++j) {
        wr[0][j]  = w_lds[(a[0][j] << 6) + lane];
        cqv[0][j] = cq_lds[a[0][j]];
    }

    // groups 0..251, 6 per iteration (ring indices compile-time)
    for (int it = 0; it < 42; ++it) {
        const int g = 6 * it;
        PROC(g + 0, 0, 2, 1, 0, 1, 1, 1, 0)
        PROC(g + 1, 1, 0, 2, 1, 0, 1, 1, 0)
        PROC(g + 2, 2, 1, 0, 0, 1, 1, 1, 0)
        PROC(g + 3, 0, 2, 1, 1, 0, 1, 1, 0)
        PROC(g + 4, 1, 0, 2, 0, 1, 1, 1, 0)
        PROC(g + 5, 2, 1, 0, 1, 0, 1, 1, 0)
    }
    // peeled tail: groups 252..255
    PROC(252, 0, 2, 1, 0, 1, 1, 1, 0)
    PROC(253, 1, 0, 2, 1, 0, 1, 1, 0)
    PROC(254, 2, 1, 0, 0, 1, 0, 1, 0)
    PROC(255, 0, 2, 1, 1, 0, 0, 0, 1)

    // epilogue: out = S . VPW + bo
    s_lds[lane] = S;
    __syncthreads();
    float acc = bo_t[lane];
    #pragma unroll 8
    for (int bb = 0; bb < VOC; ++bb)
        acc = fmaf(s_lds[bb], vpw_t[bb * VOC + lane], acc);
    out[(long)b * VOC + lane] = acc;
}

extern "C" void kernel_launch(void* const* d_in, const int* in_sizes, int n_in,
                              void* d_out, int out_size, void* d_ws, size_t ws_size,
                              hipStream_t stream)
{
    const int*   seq   = (const int*)  d_in[0];
    const float* embed = (const float*)d_in[1];
    const float* w1    = (const float*)d_in[2];
    const float* b1    = (const float*)d_in[3];
    const float* w2    = (const float*)d_in[4];
    const float* b2    = (const float*)d_in[5];
    const float* ln_g  = (const float*)d_in[6];
    const float* ln_b  = (const float*)d_in[7];
    const float* wk    = (const float*)d_in[8];
    const float* wv    = (const float*)d_in[9];
    const float* wq    = (const float*)d_in[10];
    const float* wrp   = (const float*)d_in[11];
    const float* brp   = (const float*)d_in[12];
    const float* wout  = (const float*)d_in[13];
    const float* bout  = (const float*)d_in[14];
    float* out = (float*)d_out;

    float* kn_t  = (float*)d_ws;
    float* v_t   = kn_t  + VOC * HH;
    float* q_t   = v_t   + VOC * HH;
    float* w_t   = q_t   + VOC * HH;
    float* cq_t  = w_t   + VOC * VOC;
    float* vpw_t = cq_t  + VOC * VOC;
    float* bo_t  = vpw_t + VOC * VOC;

    const int B = in_sizes[0] / LSEQ;   // 256

    hipLaunchKernelGGL(build_tables, dim3(VOC), dim3(H2), 0, stream,
                       embed, w1, b1, w2, b2, ln_g, ln_b, wk, wv, wq,
                       kn_t, v_t, q_t);
    hipLaunchKernelGGL(build_dots, dim3(2 * VOC), dim3(VOC), 0, stream,
                       kn_t, q_t, w_t, cq_t);
    hipLaunchKernelGGL(build_head, dim3(VOC), dim3(VOC), 0, stream,
                       v_t, wrp, brp, wout, bout, vpw_t, bo_t);
    hipLaunchKernelGGL(delta_s_scan, dim3(B), dim3(HH), 0, stream,
                       seq, w_t, cq_t, vpw_t, bo_t, out);
}

// Round 12
// 197.610 us; speedup vs baseline: 2.2964x; 1.2441x over previous
//
#include <hip/hip_runtime.h>
#include <hip/hip_bf16.h>

#define HH   64
#define H2   128
#define VOC  64
#define LSEQ 2048

// ---------------------------------------------------------------------------
// Kernel 1: collapse embed -> FFN -> LN -> {kn, v, q} projections into
// per-token tables (VOCAB=64 entries of H=64 floats each).  (unchanged)
// ---------------------------------------------------------------------------
__global__ __launch_bounds__(128) void build_tables(
    const float* __restrict__ embed, const float* __restrict__ w1, const float* __restrict__ b1,
    const float* __restrict__ w2, const float* __restrict__ b2,
    const float* __restrict__ ln_g, const float* __restrict__ ln_b,
    const float* __restrict__ wk, const float* __restrict__ wv, const float* __restrict__ wq,
    float* __restrict__ kn_t, float* __restrict__ v_t, float* __restrict__ q_t)
{
    const int tok = blockIdx.x;
    const int tid = threadIdx.x;
    __shared__ float e_lds[HH];
    __shared__ float h_lds[H2];
    __shared__ float hs_lds[HH];

    if (tid < HH) e_lds[tid] = embed[tok * HH + tid];
    __syncthreads();

    {
        float s = b1[tid];
        #pragma unroll 8
        for (int i = 0; i < HH; ++i) s = fmaf(e_lds[i], w1[i * H2 + tid], s);
        h_lds[tid] = fmaxf(s, 0.f);
    }
    __syncthreads();

    if (tid < HH) {
        float f = b2[tid];
        #pragma unroll 8
        for (int j = 0; j < H2; ++j) f = fmaf(h_lds[j], w2[j * HH + tid], f);
        float x = e_lds[tid] + f;
        float sum = x, sq = x * x;
        #pragma unroll
        for (int m = 1; m < 64; m <<= 1) { sum += __shfl_xor(sum, m); sq += __shfl_xor(sq, m); }
        float mu  = sum * (1.f / HH);
        float var = sq * (1.f / HH) - mu * mu;
        hs_lds[tid] = (x - mu) * rsqrtf(var + 1e-5f) * ln_g[tid] + ln_b[tid];
    }
    __syncthreads();

    if (tid < HH) {
        float k = 0.f, v = 0.f, q = 0.f;
        #pragma unroll 8
        for (int j = 0; j < HH; ++j) {
            float h = hs_lds[j];
            k = fmaf(h, wk[j * HH + tid], k);
            v = fmaf(h, wv[j * HH + tid], v);
            q = fmaf(h, wq[j * HH + tid], q);
        }
        float kk = k * k;
        #pragma unroll
        for (int m = 1; m < 64; m <<= 1) kk += __shfl_xor(kk, m);
        float kn = k / fmaxf(sqrtf(kk), 1e-12f);
        kn_t[tok * HH + tid] = kn;
        v_t [tok * HH + tid] = v;
        q_t [tok * HH + tid] = q;
    }
}

// ---------------------------------------------------------------------------
// Kernel 1b: blocks 0..63:   W[a][b]  = kn_a . kn_b   (symmetric Gram table)
//            blocks 64..127: CQ[a][b] = q_a  . kn_b
// ---------------------------------------------------------------------------
__global__ __launch_bounds__(64) void build_dots(
    const float* __restrict__ kn_t, const float* __restrict__ q_t,
    float* __restrict__ w_t, float* __restrict__ cq_t)
{
    const int aa = blockIdx.x, b = threadIdx.x;
    const bool isW = (aa < VOC);
    const int a = isW ? aa : aa - VOC;
    const float* xrow = isW ? (kn_t + a * HH) : (q_t + a * HH);
    __shared__ float xa[HH];
    xa[b] = xrow[b];
    __syncthreads();
    const float4* kav = (const float4*)xa;
    const float4* kbv = (const float4*)(kn_t + b * HH);
    float4 s = {0.f, 0.f, 0.f, 0.f};
    #pragma unroll
    for (int j = 0; j < 16; ++j) {
        float4 x = kav[j], y = kbv[j];
        s.x = fmaf(x.x, y.x, s.x); s.y = fmaf(x.y, y.y, s.y);
        s.z = fmaf(x.z, y.z, s.z); s.w = fmaf(x.w, y.w, s.w);
    }
    float r = (s.x + s.y) + (s.z + s.w);
    (isW ? w_t : cq_t)[a * VOC + b] = r;
}

// ---------------------------------------------------------------------------
// Kernel 1c: head tables.  VPW[b][o] = (v_b @ wrp) @ wout ; bo = brp@wout+bout
// ---------------------------------------------------------------------------
__global__ __launch_bounds__(64) void build_head(
    const float* __restrict__ v_t, const float* __restrict__ wrp, const float* __restrict__ brp,
    const float* __restrict__ wout, const float* __restrict__ bout,
    float* __restrict__ vpw_t, float* __restrict__ bo_t)
{
    const int b = blockIdx.x, o = threadIdx.x;
    __shared__ float vrow[HH], vp[HH];
    vrow[o] = v_t[b * HH + o];
    __syncthreads();
    float s = 0.f;
    #pragma unroll 8
    for (int i = 0; i < HH; ++i) s = fmaf(vrow[i], wrp[i * HH + o], s);
    vp[o] = s;
    __syncthreads();
    float s2 = 0.f;
    #pragma unroll 8
    for (int i = 0; i < HH; ++i) s2 = fmaf(vp[i], wout[i * VOC + o], s2);
    vpw_t[b * VOC + o] = s2;
    if (b == 0) {
        float t = bout[o];
        #pragma unroll 8
        for (int i = 0; i < HH; ++i) t = fmaf(brp[i], wout[i * VOC + o], t);
        bo_t[o] = t;
    }
}

// ---------------------------------------------------------------------------
// Kernel 2: DS-cached token-bucketed backward gamma scan.  One wave/batch.
// Invariant: DS = W . S  (lane b holds DS_b).  Per backward step t:
//   gamma_t = CQ[qtok][a_t] - DS[a_t] - sum_{j'<j in-group} W[a_j][a_j'] gamma_j'
//   DS += gamma_t * Wrow[a_t]      (W symmetric: col == row)  -- vector FMA
//   S[a_t] += gamma_t
// No cross-lane reduction anywhere; the serial chain is readlane -> 7-layer
// triangular solve -> 8 FMAs.  W rows + reversed tokens ring-prefetched.
// ---------------------------------------------------------------------------
#define RL(x, s)  __builtin_bit_cast(float, __builtin_amdgcn_readlane(__builtin_bit_cast(int, x), (s)))

// tokens of group g live at seq_rev[8g .. 8g+7] (two aligned int4s)
#define LDTOK(SLOT, G)                                                       \
{                                                                            \
    int4 p0_ = seqr4[2 * (G)];                                               \
    int4 p1_ = seqr4[2 * (G) + 1];                                           \
    sa[SLOT][0] = __builtin_amdgcn_readfirstlane(p0_.x);                     \
    sa[SLOT][1] = __builtin_amdgcn_readfirstlane(p0_.y);                     \
    sa[SLOT][2] = __builtin_amdgcn_readfirstlane(p0_.z);                     \
    sa[SLOT][3] = __builtin_amdgcn_readfirstlane(p0_.w);                     \
    sa[SLOT][4] = __builtin_amdgcn_readfirstlane(p1_.x);                     \
    sa[SLOT][5] = __builtin_amdgcn_readfirstlane(p1_.y);                     \
    sa[SLOT][6] = __builtin_amdgcn_readfirstlane(p1_.z);                     \
    sa[SLOT][7] = __builtin_amdgcn_readfirstlane(p1_.w);                     \
}

#define LDW(WS, TS)                                                          \
{                                                                            \
    _Pragma("unroll")                                                        \
    for (int j = 0; j < 8; ++j)                                              \
        wr[WS][j] = w_lds[(sa[TS][j] << 6) + lane];                          \
}

// PROC: group G.  ST=G%3 tokens, SP=(G+2)%3 token-prefetch dest, SNT=(G+1)%3
// tokens feeding W-row prefetch, SC=G%2 rows, SN=(G+1)%2.  TAIL masks j=7.
#define PROC(G, ST, SP, SNT, SC, SN, PT, PW, TAIL)                           \
{                                                                            \
    if (PT) LDTOK(SP, (G) + 2)                                               \
    if (PW) LDW(SN, SNT)                                                     \
    float din_[8], cqv_[8];                                                  \
    _Pragma("unroll")                                                        \
    for (int j = 0; j < 8; ++j) din_[j] = RL(DS, sa[ST][j]);                 \
    _Pragma("unroll")                                                        \
    for (int j = 0; j < 8; ++j) cqv_[j] = RL(CQ, sa[ST][j]);                 \
    float gm_[8];                                                            \
    float tS_ = 0.f;                                                         \
    _Pragma("unroll")                                                        \
    for (int j = 0; j < 8; ++j) {                                            \
        float g0_ = cqv_[j] - din_[j];                                       \
        _Pragma("unroll")                                                    \
        for (int j2 = 0; j2 < j; ++j2) {                                     \
            float G_ = RL(wr[SC][j], sa[ST][j2]);                            \
            g0_ = fmaf(-G_, gm_[j2], g0_);                                   \
        }                                                                    \
        gm_[j] = g0_;                                                        \
        if (!(TAIL) || j < 7) {                                              \
            DS = fmaf(g0_, wr[SC][j], DS);                                   \
            tS_ += (lane == sa[ST][j]) ? g0_ : 0.f;                          \
        }                                                                    \
    }                                                                        \
    S += tS_;                                                                \
}

__global__ __launch_bounds__(64) void delta_ds_scan(
    const int* __restrict__ seq,
    const float* __restrict__ w_t, const float* __restrict__ cq_t,
    const float* __restrict__ vpw_t, const float* __restrict__ bo_t,
    float* __restrict__ out)
{
    __shared__ __align__(16) float w_lds[VOC * VOC];   // 16 KB
    __shared__ __align__(16) int   seq_rev[LSEQ];      // 8 KB, reversed tokens
    __shared__ float s_lds[VOC];

    const int b    = blockIdx.x;
    const int lane = threadIdx.x;
    const int* __restrict__ seq_b = seq + (long)b * LSEQ;

    // stage W table + reversed token stream: seq_rev[m] = seq_b[max(2046-m,0)]
    {
        const float4* s1 = (const float4*)w_t; float4* d1 = (float4*)w_lds;
        #pragma unroll
        for (int r = 0; r < 16; ++r) d1[lane + 64 * r] = s1[lane + 64 * r];
        #pragma unroll 4
        for (int r = 0; r < 32; ++r) {
            int m = r * 64 + lane;
            int idx = 2046 - m;
            seq_rev[m] = seq_b[idx < 0 ? 0 : idx];
        }
    }
    __syncthreads();

    float CQ;
    { const int qtok = seq_b[LSEQ - 1]; CQ = cq_t[qtok * VOC + lane]; }

    float DS = 0.f, S = 0.f;
    int   sa[3][8];
    float wr[2][8];
    const int4* seqr4 = (const int4*)seq_rev;

    // prologue: tokens for groups 0,1; W-rows for group 0
    LDTOK(0, 0)
    LDTOK(1, 1)
    LDW(0, 0)

    // groups 0..251, 6 per iteration (ring indices compile-time)
    for (int it = 0; it < 42; ++it) {
        const int g = 6 * it;
        PROC(g + 0, 0, 2, 1, 0, 1, 1, 1, 0)
        PROC(g + 1, 1, 0, 2, 1, 0, 1, 1, 0)
        PROC(g + 2, 2, 1, 0, 0, 1, 1, 1, 0)
        PROC(g + 3, 0, 2, 1, 1, 0, 1, 1, 0)
        PROC(g + 4, 1, 0, 2, 0, 1, 1, 1, 0)
        PROC(g + 5, 2, 1, 0, 1, 0, 1, 1, 0)
    }
    // peeled tail: groups 252..255 (255 has 7 real steps, j=7 masked)
    PROC(252, 0, 2, 1, 0, 1, 1, 1, 0)
    PROC(253, 1, 0, 2, 1, 0, 1, 1, 0)
    PROC(254, 2, 1, 0, 0, 1, 0, 1, 0)
    PROC(255, 0, 2, 1, 1, 0, 0, 0, 1)

    // epilogue: out = S . VPW + bo
    s_lds[lane] = S;
    __syncthreads();
    float acc = bo_t[lane];
    #pragma unroll 8
    for (int bb = 0; bb < VOC; ++bb)
        acc = fmaf(s_lds[bb], vpw_t[bb * VOC + lane], acc);
    out[(long)b * VOC + lane] = acc;
}

extern "C" void kernel_launch(void* const* d_in, const int* in_sizes, int n_in,
                              void* d_out, int out_size, void* d_ws, size_t ws_size,
                              hipStream_t stream)
{
    const int*   seq   = (const int*)  d_in[0];
    const float* embed = (const float*)d_in[1];
    const float* w1    = (const float*)d_in[2];
    const float* b1    = (const float*)d_in[3];
    const float* w2    = (const float*)d_in[4];
    const float* b2    = (const float*)d_in[5];
    const float* ln_g  = (const float*)d_in[6];
    const float* ln_b  = (const float*)d_in[7];
    const float* wk    = (const float*)d_in[8];
    const float* wv    = (const float*)d_in[9];
    const float* wq    = (const float*)d_in[10];
    const float* wrp   = (const float*)d_in[11];
    const float* brp   = (const float*)d_in[12];
    const float* wout  = (const float*)d_in[13];
    const float* bout  = (const float*)d_in[14];
    float* out = (float*)d_out;

    float* kn_t  = (float*)d_ws;
    float* v_t   = kn_t  + VOC * HH;
    float* q_t   = v_t   + VOC * HH;
    float* w_t   = q_t   + VOC * HH;
    float* cq_t  = w_t   + VOC * VOC;
    float* vpw_t = cq_t  + VOC * VOC;
    float* bo_t  = vpw_t + VOC * VOC;

    const int B = in_sizes[0] / LSEQ;   // 256

    hipLaunchKernelGGL(build_tables, dim3(VOC), dim3(H2), 0, stream,
                       embed, w1, b1, w2, b2, ln_g, ln_b, wk, wv, wq,
                       kn_t, v_t, q_t);
    hipLaunchKernelGGL(build_dots, dim3(2 * VOC), dim3(VOC), 0, stream,
                       kn_t, q_t, w_t, cq_t);
    hipLaunchKernelGGL(build_head, dim3(VOC), dim3(VOC), 0, stream,
                       v_t, wrp, brp, wout, bout, vpw_t, bo_t);
    hipLaunchKernelGGL(delta_ds_scan, dim3(B), dim3(HH), 0, stream,
                       seq, w_t, cq_t, vpw_t, bo_t, out);
}